// Round 6
// baseline (207.776 us; speedup 1.0000x reference)
//
#include <hip/hip_runtime.h>

// VQ-VAE vector quantizer, MI355X (gfx950).
//   inputs : z (8,256,16,16,16) fp32, codebook (1024,256) fp32
//   output : quant (8,256,16,16,16) ++ idx (8,16,16,16) ++ loss (1), fp32 flat
//
// Round 12: z-tile in LDS. r7-r11 showed Phase-C experiments and occupancy
//   (8 vs 16 waves/CU) move nothing: the kernel is bound by per-wave latency
//   chains of STRIDED z gathers (stride 16KB), read 4x per element across
//   Sz / A-frags / Phase-D dots (256 scalar loads per candidate!) / Phase E.
//   Fix: each block stages its 64-token x 256-dim z-tile (64KB fp32) into
//   LDS once, coalesced (16B/lane along tokens); all later phases read LDS.
//   zt[tok][257] padding -> bank=(tok+d)%32: E 2-way-free, D spread, A/Sz
//   <=2-way. Exact fp32 bits stored -> all verified __fadd_rn/fmaf chains
//   unchanged. LDS ~108KB -> 1 block/CU (8 waves; proven perf-neutral).
//   Phase C keeps r11's verified form (reg round-trip staging, g x kh split,
//   atomicAdd append, per-half aminv). Keeps: parallel prep, fused loss,
//   float4 e-row gathers.

#define K_CODES 1024
#define DIM 256
#define N_TOK 32768
#define SPATIAL 4096
#define TOK_BLK 64
#define NBLK (N_TOK / TOK_BLK)
#define CAP 28
#define MARGIN 1e-3f
#define ZLD 257  // z-tile row stride (floats): bank = (tok + d) % 32

typedef __attribute__((ext_vector_type(8))) short short8;
typedef __attribute__((ext_vector_type(4))) float float4v;

// ws layout in floats
#define WS_LOSS 0
#define WS_CNT 8      // unsigned completion counter (byte 32)
#define WS_E2 16      // 1024 floats: Se[k] (np pairwise)
#define WS_EB 2048    // 262144 bf16: codebook, B-fragment order

#define O_IDX (8 * DIM * SPATIAL)  // 8388608
#define O_LOSS (O_IDX + N_TOK)     // 8421376

__device__ __forceinline__ short f2bf(float v) {  // RTNE fp32->bf16 bits
  unsigned u = __float_as_uint(v);
  u = (u + 0x7fffu + ((u >> 16) & 1u)) >> 16;
  return (short)u;
}

// prep: Se[k] np-pairwise (exact order, parallelized); codebook -> bf16 in
// MFMA B-fragment order, 16B chunk stores.  (verified rounds 7-11)
__global__ __launch_bounds__(256) void prep_kernel(const float* __restrict__ e,
                                                   float* __restrict__ ws) {
  __shared__ float sq[DIM];
  __shared__ __align__(16) short sbf[DIM];
  __shared__ float chv[16];
  int k = blockIdx.x, d = threadIdx.x;
  float v = e[k * DIM + d];
  sbf[d] = f2bf(v);
  sq[d] = __fmul_rn(v, v);
  __syncthreads();
  if (d < 32) {  // 16B chunk stores of the fragment layout
    int f = d >> 2, q = d & 3;
    int stage = k >> 6, ct = (k >> 4) & 3, nn = k & 15;
    short8 chunk = *(const short8*)(sbf + f * 32 + q * 8);
    int off8 = ((stage * 4 + ct) * 8 + f) * 64 + q * 16 + nn;
    ((short8*)(ws + WS_EB))[off8] = chunk;
  }
  if (d < 16) {  // chain (blk=d>>3, j=d&7): exact np serial order i=0..15
    int blkb = d >> 3, j = d & 7;
    const float* x = sq + blkb * 128;
    float c = x[j];
#pragma unroll
    for (int i = 1; i < 16; i++) c = __fadd_rn(c, x[i * 8 + j]);
    chv[d] = c;
  }
  __syncthreads();
  if (d == 0) {  // exact np_pairwise128 combine tree, then blk0+blk1
    float a0 = __fadd_rn(__fadd_rn(chv[0], chv[1]), __fadd_rn(chv[2], chv[3]));
    float a1 = __fadd_rn(__fadd_rn(chv[4], chv[5]), __fadd_rn(chv[6], chv[7]));
    float resA = __fadd_rn(a0, a1);
    float b0 = __fadd_rn(__fadd_rn(chv[8], chv[9]), __fadd_rn(chv[10], chv[11]));
    float b1 = __fadd_rn(__fadd_rn(chv[12], chv[13]), __fadd_rn(chv[14], chv[15]));
    float resB = __fadd_rn(b0, b1);
    ws[WS_E2 + k] = __fadd_rn(resA, resB);
    if (k == 0) {
      ws[WS_LOSS] = 0.f;
      ((unsigned*)ws)[WS_CNT] = 0u;
    }
  }
}

__global__ __launch_bounds__(512, 2) void main_kernel(const float* __restrict__ z,
                                                      const float* __restrict__ e,
                                                      float* __restrict__ ws,
                                                      float* __restrict__ out) {
  __shared__ __align__(16) short Bst[64 * 256];   // 32 KB, fragment order
  __shared__ float zt[TOK_BLK * ZLD];             // 64.25 KB z-tile [tok][257]
  __shared__ unsigned short cand[TOK_BLK][CAP];
  __shared__ float cands[TOK_BLK][CAP];
  __shared__ float aminv[2][TOK_BLK];  // per-k-half final approx min
  __shared__ int cnt[TOK_BLK];
  __shared__ float Szp[2][TOK_BLK];    // per-128-dim-block Sz partials
  __shared__ int mini_sh[TOK_BLK];
  __shared__ float red[8];

  int tid = threadIdx.x, w = tid >> 6, lane = tid & 63;
  int quad = lane >> 4, nn = lane & 15;
  int g = w & 3, kh = w >> 2;  // token group (16 tokens), codebook half
  int n0 = blockIdx.x * TOK_BLK;
  int b = n0 >> 12, s0 = n0 & 4095;
  const float* zb = z + (size_t)b * DIM * SPATIAL + s0;
  const float* Se = ws + WS_E2;
  const uint4* eBg = (const uint4*)(ws + WS_EB);
  if (tid < TOK_BLK) cnt[tid] = 0;

  // ---- z-tile load: 4096 float4 chunks, coalesced along tokens.
  //      chunk c -> d = c>>4, tok4 = (c&15)*4; scatter 4 scalars to rows. ----
#pragma unroll
  for (int it = 0; it < 8; it++) {
    int c = it * 512 + tid;
    int d = c >> 4, t4 = (c & 15) << 2;
    float4 v4 = *(const float4*)(zb + (size_t)d * SPATIAL + t4);
    zt[(t4 + 0) * ZLD + d] = v4.x;
    zt[(t4 + 1) * ZLD + d] = v4.y;
    zt[(t4 + 2) * ZLD + d] = v4.z;
    zt[(t4 + 3) * ZLD + d] = v4.w;
  }
  __syncthreads();  // z-tile ready (also publishes cnt=0)

  // ---- Sz partial (exact np pairwise) from LDS: wave kh does dim-block kh
  //      (128 d) for its 16 tokens. Lane (quad,nn): chains j = quad*2+{0,1}
  //      of token g*16+nn. Merge tree = exact np pairing (r8/r11-verified):
  //      p=(c2q+c2q+1); xor16 -> (p0+p1)|(p2+p3); xor32 -> blk result. ----
  {
    const float* zp = zt + (g * 16 + nn) * ZLD + kh * 128;
    float r0, r1;
    {
      int j0 = quad * 2;
      float v0 = zp[j0];
      float v1 = zp[j0 + 1];
      r0 = __fmul_rn(v0, v0);
      r1 = __fmul_rn(v1, v1);
      for (int i = 1; i < 16; i++) {
        v0 = zp[i * 8 + j0];
        v1 = zp[i * 8 + j0 + 1];
        r0 = __fadd_rn(r0, __fmul_rn(v0, v0));
        r1 = __fadd_rn(r1, __fmul_rn(v1, v1));
      }
    }
    float p = __fadd_rn(r0, r1);                    // (c_{2q} + c_{2q+1})
    float s1 = __fadd_rn(p, __shfl_xor(p, 16));     // (p0+p1) | (p2+p3)
    float s2 = __fadd_rn(s1, __shfl_xor(s1, 32));   // np_pairwise128 result
    if (quad == 0) Szp[kh][g * 16 + nn] = s2;
  }

  // ---- A fragments (z -> bf16) from LDS: token m = g*16+nn,
  //      frag f holds k-dim d = f*32 + quad*8 + j ----
  const float* zrowA = zt + (g * 16 + nn) * ZLD;
  short8 A[8];
#pragma unroll
  for (int f = 0; f < 8; f++) {
    short8 a;
#pragma unroll
    for (int j = 0; j < 8; j++) a[j] = f2bf(zrowA[f * 32 + quad * 8 + j]);
    A[f] = a;
  }

  // ---- Phase C: MFMA filter over 16 stages of 64 codes. r6/r11 staging
  //      form (loads consumed inside the window -- compiler pipelines it).
  //      Wave (g,kh) computes ct = kh*2+{0,1} each stage: 16 MFMA. ----
  float thr[4] = {3.4e38f, 3.4e38f, 3.4e38f, 3.4e38f};
  for (int stage = 0; stage < 16; stage++) {
    __syncthreads();  // prior-stage LDS reads done
#pragma unroll
    for (int i = 0; i < 4; i++)  // 32 KB via 512 threads: reg round-trip
      ((uint4*)Bst)[i * 512 + tid] = eBg[(size_t)stage * 2048 + i * 512 + tid];
    __syncthreads();  // data ready

    for (int ctl = 0; ctl < 2; ctl++) {
      int ct = kh * 2 + ctl;
      int kbase = stage * 64 + ct * 16;
      float4v C = {0.f, 0.f, 0.f, 0.f};
      const short8* Bp = (const short8*)Bst + ct * 8 * 64;
#pragma unroll
      for (int f = 0; f < 8; f++) {
        short8 Bf = Bp[f * 64 + lane];  // ds_read_b128, conflict-free
        C = __builtin_amdgcn_mfma_f32_16x16x32_bf16(A[f], Bf, C, 0, 0, 0);
      }
      float SeK = Se[kbase + nn];  // col = code = nn
      float sv[4];
      bool pr[4];
#pragma unroll
      for (int r = 0; r < 4; r++) {  // row = token = quad*4 + r
        float s = fmaf(-2.f, C[r], SeK);
        float m = s;  // rowmin across the 16 lanes of this row
        m = fminf(m, __shfl_xor(m, 1, 16));
        m = fminf(m, __shfl_xor(m, 2, 16));
        m = fminf(m, __shfl_xor(m, 4, 16));
        m = fminf(m, __shfl_xor(m, 8, 16));
        thr[r] = fminf(thr[r], m);
        sv[r] = s;
        pr[r] = s < thr[r] + MARGIN;
      }
      if (__ballot(pr[0] | pr[1] | pr[2] | pr[3])) {  // rare path
#pragma unroll
        for (int r = 0; r < 4; r++) {
          unsigned long long bl = __ballot(pr[r]);
          unsigned grp = (unsigned)((bl >> (quad * 16)) & 0xffffULL);
          if (grp) {  // quad-uniform
            int tb = g * 16 + quad * 4 + r;
            int base = 0;
            if (nn == 0) base = atomicAdd(&cnt[tb], __popc(grp));
            base = __shfl(base, quad * 16);  // broadcast from quad's lane 0
            if (pr[r]) {
              int pos = base + __popc(grp & ((1u << nn) - 1u));
              if (pos < CAP) {
                cand[tb][pos] = (unsigned short)(kbase + nn);
                cands[tb][pos] = sv[r];
              }
            }
          }
        }
      }
    }
  }
  // publish per-(token, k-half) final approx min
#pragma unroll
  for (int r = 0; r < 4; r++)
    if (nn == 0) aminv[kh][g * 16 + quad * 4 + r] = thr[r];
  __syncthreads();  // candidates + aminv + Szp ready across the kh pairs

  // ---- Phase D: exact recheck, z from LDS. Wave w owns tokens w*8..w*8+7;
  //      lane = (token tl, oct); candidate slots oct::8 (r9/r11-verified).
  //      Lex-min (D,k) over the set is append-order-independent. ----
  int tl = lane >> 3, oct = lane & 7;
  int tb = w * 8 + tl;
  int cc = cnt[tb];
  int cl = cc < CAP ? cc : CAP;
  float bestD = 3.4e38f;
  int bestk = 0x7fffffff;
  float SznT = __fadd_rn(Szp[0][tb], Szp[1][tb]);  // exact: blk0 + blk1
  {
    const float* zp = zt + tb * ZLD;
    float amin = fminf(aminv[0][tb], aminv[1][tb]);
    for (int c = oct; c < cl; c += 8) {
      if (cands[tb][c] >= amin + MARGIN) continue;  // pruned
      int k = cand[tb][c];
      const float* er = e + (size_t)k * DIM;
      float acc = 0.f;
#pragma unroll 4
      for (int dd = 0; dd < DIM; dd += 4) {
        float4 e4 = *(const float4*)(er + dd);
        acc = fmaf(zp[dd + 0], e4.x, acc);
        acc = fmaf(zp[dd + 1], e4.y, acc);
        acc = fmaf(zp[dd + 2], e4.z, acc);
        acc = fmaf(zp[dd + 3], e4.w, acc);
      }
      float D = __fsub_rn(__fadd_rn(SznT, Se[k]), __fmul_rn(2.f, acc));
      if (D < bestD || (D == bestD && k < bestk)) { bestD = D; bestk = k; }
    }
  }
#pragma unroll
  for (int off = 4; off >= 1; off >>= 1) {  // merge the 8 lanes per token
    float oD = __shfl_down(bestD, off, 8);
    int ok = __shfl_down(bestk, off, 8);
    if (oD < bestD || (oD == bestD && ok < bestk)) { bestD = oD; bestk = ok; }
  }
  if (oct == 0 && cc <= CAP) {
    mini_sh[tb] = bestk;
    out[O_IDX + n0 + tb] = (float)bestk;
  }
  // overflow tokens: exact full scan by the whole wave (deterministic)
  for (int t = 0; t < 8; t++) {
    int tb2 = w * 8 + t;
    if (cnt[tb2] > CAP) {
      const float* zq = zt + tb2 * ZLD;
      float Szn = __fadd_rn(Szp[0][tb2], Szp[1][tb2]);
      float bD = 3.4e38f;
      int bk = 0x7fffffff;
      for (int k = lane; k < K_CODES; k += 64) {
        const float* er = e + (size_t)k * DIM;
        float acc = 0.f;
#pragma unroll 4
        for (int dd = 0; dd < DIM; dd += 4) {
          float4 e4 = *(const float4*)(er + dd);
          acc = fmaf(zq[dd + 0], e4.x, acc);
          acc = fmaf(zq[dd + 1], e4.y, acc);
          acc = fmaf(zq[dd + 2], e4.z, acc);
          acc = fmaf(zq[dd + 3], e4.w, acc);
        }
        float D = __fsub_rn(__fadd_rn(Szn, Se[k]), __fmul_rn(2.f, acc));
        if (D < bD || (D == bD && k < bk)) { bD = D; bk = k; }
      }
#pragma unroll
      for (int m = 1; m < 64; m <<= 1) {
        float oD = __shfl_xor(bD, m);
        int ok = __shfl_xor(bk, m);
        if (oD < bD || (oD == bD && ok < bk)) { bD = oD; bk = ok; }
      }
      if (lane == 0) {
        mini_sh[tb2] = bk;
        out[O_IDX + n0 + tb2] = (float)bk;
      }
    }
  }
  __syncthreads();

  // ---- Phase E: quant gather + store + loss; z from LDS (bank-free:
  //      (lane + d) % 32 two-way), e-row read as float4. ----
  int mten = mini_sh[lane];  // lane = token
  const float* erow = e + (size_t)mten * DIM;
  const float* zrow = zt + lane * ZLD;
  float* op = out + (size_t)b * DIM * SPATIAL + s0;
  float sumsq = 0.f;
#pragma unroll 2
  for (int i4 = 0; i4 < 32; i4 += 4) {
    int d = w * 32 + i4;  // wave-uniform d, 16B-aligned
    float4 v4 = *(const float4*)(erow + d);
#pragma unroll
    for (int m = 0; m < 4; m++) {
      float v = (m == 0) ? v4.x : (m == 1) ? v4.y : (m == 2) ? v4.z : v4.w;
      float zv = zrow[d + m];
      float df = __fsub_rn(v, zv);
      sumsq = fmaf(df, df, sumsq);
      op[(size_t)(d + m) * SPATIAL + lane] = v;  // coalesced 64-wide store
    }
  }
#pragma unroll
  for (int o = 32; o > 0; o >>= 1) sumsq += __shfl_down(sumsq, o, 64);
  if (lane == 0) red[w] = sumsq;
  __syncthreads();
  if (tid == 0) {
    float rs = ((red[0] + red[1]) + (red[2] + red[3])) +
               ((red[4] + red[5]) + (red[6] + red[7]));
    atomicAdd(ws + WS_LOSS, rs);
    __threadfence();  // loss add globally visible before counter bump
    unsigned t = atomicAdd((unsigned*)ws + WS_CNT, 1u);
    if (t == NBLK - 1) {  // last block publishes loss
      float total = atomicAdd(ws + WS_LOSS, 0.f);  // device-scope read
      out[O_LOSS] = 1.25f * total / 8388608.f;
    }
  }
}

extern "C" void kernel_launch(void* const* d_in, const int* in_sizes, int n_in,
                              void* d_out, int out_size, void* d_ws, size_t ws_size,
                              hipStream_t stream) {
  const float* z = (const float*)d_in[0];
  const float* e = (const float*)d_in[1];
  float* ws = (float*)d_ws;
  float* out = (float*)d_out;

  prep_kernel<<<K_CODES, 256, 0, stream>>>(e, ws);
  main_kernel<<<NBLK, 512, 0, stream>>>(z, e, ws, out);
}

// Round 7
// 202.118 us; speedup vs baseline: 1.0280x; 1.0280x over previous
//
#include <hip/hip_runtime.h>

// VQ-VAE vector quantizer, MI355X (gfx950).
//   inputs : z (8,256,16,16,16) fp32, codebook (1024,256) fp32
//   output : quant (8,256,16,16,16) ++ idx (8,16,16,16) ++ loss (1), fp32 flat
//
// Round 13: base = r11 (best total 203.4; 512 thr, g x kh split, reg
//   round-trip staging). Change: Phase C's two cts per wave per stage are
//   PAIRED -- C0/C1 MFMA chains interleaved (two independent dep-chains in
//   flight, 2x outstanding ds_reads), then all 8 rowmin shfl chains
//   interleaved, then the two append blocks in r11's exact order.
//   Rationale: r6-r12 falsified staging latency / occupancy / z-gathers;
//   per-CU throughput invariant with ALL pipes <25% busy points at
//   dependency-chain dead time (8 dep MFMAs + 4 dep shfl_xor per ct) that
//   the compiler cannot overlap across cts (divergent append in between).
//   Scores bit-identical to r11 (per-C f-order and thr sequencing
//   preserved) -> candidate sets, recheck, outputs unchanged.

#define K_CODES 1024
#define DIM 256
#define N_TOK 32768
#define SPATIAL 4096
#define TOK_BLK 64
#define NBLK (N_TOK / TOK_BLK)
#define CAP 28
#define MARGIN 1e-3f

typedef __attribute__((ext_vector_type(8))) short short8;
typedef __attribute__((ext_vector_type(4))) float float4v;

// ws layout in floats
#define WS_LOSS 0
#define WS_CNT 8      // unsigned completion counter (byte 32)
#define WS_E2 16      // 1024 floats: Se[k] (np pairwise)
#define WS_EB 2048    // 262144 bf16: codebook, B-fragment order

#define O_IDX (8 * DIM * SPATIAL)  // 8388608
#define O_LOSS (O_IDX + N_TOK)     // 8421376

__device__ __forceinline__ short f2bf(float v) {  // RTNE fp32->bf16 bits
  unsigned u = __float_as_uint(v);
  u = (u + 0x7fffu + ((u >> 16) & 1u)) >> 16;
  return (short)u;
}

// prep: Se[k] np-pairwise (exact order, parallelized); codebook -> bf16 in
// MFMA B-fragment order, 16B chunk stores.  (verified rounds 7-12)
__global__ __launch_bounds__(256) void prep_kernel(const float* __restrict__ e,
                                                   float* __restrict__ ws) {
  __shared__ float sq[DIM];
  __shared__ __align__(16) short sbf[DIM];
  __shared__ float chv[16];
  int k = blockIdx.x, d = threadIdx.x;
  float v = e[k * DIM + d];
  sbf[d] = f2bf(v);
  sq[d] = __fmul_rn(v, v);
  __syncthreads();
  if (d < 32) {  // 16B chunk stores of the fragment layout
    int f = d >> 2, q = d & 3;
    int stage = k >> 6, ct = (k >> 4) & 3, nn = k & 15;
    short8 chunk = *(const short8*)(sbf + f * 32 + q * 8);
    int off8 = ((stage * 4 + ct) * 8 + f) * 64 + q * 16 + nn;
    ((short8*)(ws + WS_EB))[off8] = chunk;
  }
  if (d < 16) {  // chain (blk=d>>3, j=d&7): exact np serial order i=0..15
    int blkb = d >> 3, j = d & 7;
    const float* x = sq + blkb * 128;
    float c = x[j];
#pragma unroll
    for (int i = 1; i < 16; i++) c = __fadd_rn(c, x[i * 8 + j]);
    chv[d] = c;
  }
  __syncthreads();
  if (d == 0) {  // exact np_pairwise128 combine tree, then blk0+blk1
    float a0 = __fadd_rn(__fadd_rn(chv[0], chv[1]), __fadd_rn(chv[2], chv[3]));
    float a1 = __fadd_rn(__fadd_rn(chv[4], chv[5]), __fadd_rn(chv[6], chv[7]));
    float resA = __fadd_rn(a0, a1);
    float b0 = __fadd_rn(__fadd_rn(chv[8], chv[9]), __fadd_rn(chv[10], chv[11]));
    float b1 = __fadd_rn(__fadd_rn(chv[12], chv[13]), __fadd_rn(chv[14], chv[15]));
    float resB = __fadd_rn(b0, b1);
    ws[WS_E2 + k] = __fadd_rn(resA, resB);
    if (k == 0) {
      ws[WS_LOSS] = 0.f;
      ((unsigned*)ws)[WS_CNT] = 0u;
    }
  }
}

__global__ __launch_bounds__(512, 4) void main_kernel(const float* __restrict__ z,
                                                      const float* __restrict__ e,
                                                      float* __restrict__ ws,
                                                      float* __restrict__ out) {
  __shared__ __align__(16) short Bst[64 * 256];  // 32 KB, fragment order
  __shared__ unsigned short cand[TOK_BLK][CAP];
  __shared__ float cands[TOK_BLK][CAP];
  __shared__ float aminv[2][TOK_BLK];  // per-k-half final approx min
  __shared__ int cnt[TOK_BLK];
  __shared__ float Szp[2][TOK_BLK];    // per-128-dim-block Sz partials
  __shared__ int mini_sh[TOK_BLK];
  __shared__ float red[8];

  int tid = threadIdx.x, w = tid >> 6, lane = tid & 63;
  int quad = lane >> 4, nn = lane & 15;
  int g = w & 3, kh = w >> 2;  // token group (16 tokens), codebook half
  int n0 = blockIdx.x * TOK_BLK;
  int b = n0 >> 12, s0 = n0 & 4095;
  const float* zb = z + (size_t)b * DIM * SPATIAL + s0;
  const float* Se = ws + WS_E2;
  const uint4* eBg = (const uint4*)(ws + WS_EB);
  if (tid < TOK_BLK) cnt[tid] = 0;

  // ---- Sz partial (exact np pairwise): wave kh does dim-block kh (128 d)
  //      for its 16 tokens. Lane (quad,nn): chains j = quad*2 + {0,1} of
  //      token g*16+nn. Merge tree = exact np pairing (r8/r11-verified). ----
  {
    const float* zp = zb + g * 16 + nn;
    float r0, r1;
    {
      int j0 = quad * 2;
      float v0 = zp[(size_t)(kh * 128 + j0) * SPATIAL];
      float v1 = zp[(size_t)(kh * 128 + j0 + 1) * SPATIAL];
      r0 = __fmul_rn(v0, v0);
      r1 = __fmul_rn(v1, v1);
      for (int i = 1; i < 16; i++) {
        v0 = zp[(size_t)(kh * 128 + i * 8 + j0) * SPATIAL];
        v1 = zp[(size_t)(kh * 128 + i * 8 + j0 + 1) * SPATIAL];
        r0 = __fadd_rn(r0, __fmul_rn(v0, v0));
        r1 = __fadd_rn(r1, __fmul_rn(v1, v1));
      }
    }
    float p = __fadd_rn(r0, r1);                    // (c_{2q} + c_{2q+1})
    float s1 = __fadd_rn(p, __shfl_xor(p, 16));     // (p0+p1) | (p2+p3)
    float s2 = __fadd_rn(s1, __shfl_xor(s1, 32));   // np_pairwise128 result
    if (quad == 0) Szp[kh][g * 16 + nn] = s2;
  }

  // ---- A fragments (z -> bf16) in registers: token m = g*16+nn,
  //      frag f holds k-dim d = f*32 + quad*8 + j ----
  int tokA = g * 16 + nn;
  short8 A[8];
#pragma unroll
  for (int f = 0; f < 8; f++) {
    short8 a;
#pragma unroll
    for (int j = 0; j < 8; j++) {
      int d = f * 32 + quad * 8 + j;
      a[j] = f2bf(zb[(size_t)d * SPATIAL + tokA]);
    }
    A[f] = a;
  }

  // ---- Phase C: MFMA filter over 16 stages of 64 codes. r11 staging form;
  //      wave (g,kh)'s two cts PAIRED: interleaved MFMA chains, interleaved
  //      rowmin chains, then appends in r11's exact thr/append order. ----
  float thr[4] = {3.4e38f, 3.4e38f, 3.4e38f, 3.4e38f};
  for (int stage = 0; stage < 16; stage++) {
    __syncthreads();  // prior-stage LDS reads done (also orders cnt=0, Szp)
#pragma unroll
    for (int i = 0; i < 4; i++)  // 32 KB via 512 threads: reg round-trip
      ((uint4*)Bst)[i * 512 + tid] = eBg[(size_t)stage * 2048 + i * 512 + tid];
    __syncthreads();  // data ready

    int ct0 = kh * 2, ct1 = kh * 2 + 1;
    int kbase0 = stage * 64 + ct0 * 16;
    int kbase1 = stage * 64 + ct1 * 16;
    float4v C0 = {0.f, 0.f, 0.f, 0.f};
    float4v C1 = {0.f, 0.f, 0.f, 0.f};
    const short8* Bp0 = (const short8*)Bst + ct0 * 8 * 64;
    const short8* Bp1 = (const short8*)Bst + ct1 * 8 * 64;
#pragma unroll
    for (int f = 0; f < 8; f++) {  // two independent chains, interleaved
      short8 B0 = Bp0[f * 64 + lane];  // ds_read_b128, conflict-free
      short8 B1 = Bp1[f * 64 + lane];
      C0 = __builtin_amdgcn_mfma_f32_16x16x32_bf16(A[f], B0, C0, 0, 0, 0);
      C1 = __builtin_amdgcn_mfma_f32_16x16x32_bf16(A[f], B1, C1, 0, 0, 0);
    }
    float SeK0 = Se[kbase0 + nn];  // col = code = nn
    float SeK1 = Se[kbase1 + nn];
    float s0[4], s1[4], m0[4], m1[4];
#pragma unroll
    for (int r = 0; r < 4; r++) {  // row = token = quad*4 + r
      s0[r] = fmaf(-2.f, C0[r], SeK0);
      s1[r] = fmaf(-2.f, C1[r], SeK1);
      m0[r] = s0[r];
      m1[r] = s1[r];
    }
#pragma unroll
    for (int dlt = 1; dlt <= 8; dlt <<= 1) {  // 8 independent rowmin chains
#pragma unroll
      for (int r = 0; r < 4; r++) {
        m0[r] = fminf(m0[r], __shfl_xor(m0[r], dlt, 16));
        m1[r] = fminf(m1[r], __shfl_xor(m1[r], dlt, 16));
      }
    }
    // ---- ct0: thr update + append (r11 order) ----
    bool pr[4];
#pragma unroll
    for (int r = 0; r < 4; r++) {
      thr[r] = fminf(thr[r], m0[r]);
      pr[r] = s0[r] < thr[r] + MARGIN;
    }
    if (__ballot(pr[0] | pr[1] | pr[2] | pr[3])) {  // rare path
#pragma unroll
      for (int r = 0; r < 4; r++) {
        unsigned long long bl = __ballot(pr[r]);
        unsigned grp = (unsigned)((bl >> (quad * 16)) & 0xffffULL);
        if (grp) {  // quad-uniform
          int tb = g * 16 + quad * 4 + r;
          int base = 0;
          if (nn == 0) base = atomicAdd(&cnt[tb], __popc(grp));
          base = __shfl(base, quad * 16);  // broadcast from quad's lane 0
          if (pr[r]) {
            int pos = base + __popc(grp & ((1u << nn) - 1u));
            if (pos < CAP) {
              cand[tb][pos] = (unsigned short)(kbase0 + nn);
              cands[tb][pos] = s0[r];
            }
          }
        }
      }
    }
    // ---- ct1: thr update + append ----
#pragma unroll
    for (int r = 0; r < 4; r++) {
      thr[r] = fminf(thr[r], m1[r]);
      pr[r] = s1[r] < thr[r] + MARGIN;
    }
    if (__ballot(pr[0] | pr[1] | pr[2] | pr[3])) {  // rare path
#pragma unroll
      for (int r = 0; r < 4; r++) {
        unsigned long long bl = __ballot(pr[r]);
        unsigned grp = (unsigned)((bl >> (quad * 16)) & 0xffffULL);
        if (grp) {  // quad-uniform
          int tb = g * 16 + quad * 4 + r;
          int base = 0;
          if (nn == 0) base = atomicAdd(&cnt[tb], __popc(grp));
          base = __shfl(base, quad * 16);  // broadcast from quad's lane 0
          if (pr[r]) {
            int pos = base + __popc(grp & ((1u << nn) - 1u));
            if (pos < CAP) {
              cand[tb][pos] = (unsigned short)(kbase1 + nn);
              cands[tb][pos] = s1[r];
            }
          }
        }
      }
    }
  }
  // publish per-(token, k-half) final approx min
#pragma unroll
  for (int r = 0; r < 4; r++)
    if (nn == 0) aminv[kh][g * 16 + quad * 4 + r] = thr[r];
  __syncthreads();  // candidates + aminv + Szp ready across the kh pairs

  // ---- Phase D: exact recheck. Wave w owns tokens w*8..w*8+7; lane =
  //      (token tl, oct); candidate slots oct::8 (r9/r11-verified).
  //      Lex-min (D,k) over the set is append-order-independent. ----
  int tl = lane >> 3, oct = lane & 7;
  int tb = w * 8 + tl;
  int cc = cnt[tb];
  int cl = cc < CAP ? cc : CAP;
  float bestD = 3.4e38f;
  int bestk = 0x7fffffff;
  float SznT = __fadd_rn(Szp[0][tb], Szp[1][tb]);  // exact: blk0 + blk1
  {
    const float* zp = zb + tb;
    float amin = fminf(aminv[0][tb], aminv[1][tb]);
    for (int c = oct; c < cl; c += 8) {
      if (cands[tb][c] >= amin + MARGIN) continue;  // pruned
      int k = cand[tb][c];
      const float* er = e + (size_t)k * DIM;
      float acc = 0.f;
#pragma unroll 4
      for (int dd = 0; dd < DIM; dd += 4) {
        float4 e4 = *(const float4*)(er + dd);
        acc = fmaf(zp[(size_t)(dd + 0) * SPATIAL], e4.x, acc);
        acc = fmaf(zp[(size_t)(dd + 1) * SPATIAL], e4.y, acc);
        acc = fmaf(zp[(size_t)(dd + 2) * SPATIAL], e4.z, acc);
        acc = fmaf(zp[(size_t)(dd + 3) * SPATIAL], e4.w, acc);
      }
      float D = __fsub_rn(__fadd_rn(SznT, Se[k]), __fmul_rn(2.f, acc));
      if (D < bestD || (D == bestD && k < bestk)) { bestD = D; bestk = k; }
    }
  }
#pragma unroll
  for (int off = 4; off >= 1; off >>= 1) {  // merge the 8 lanes per token
    float oD = __shfl_down(bestD, off, 8);
    int ok = __shfl_down(bestk, off, 8);
    if (oD < bestD || (oD == bestD && ok < bestk)) { bestD = oD; bestk = ok; }
  }
  if (oct == 0 && cc <= CAP) {
    mini_sh[tb] = bestk;
    out[O_IDX + n0 + tb] = (float)bestk;
  }
  // overflow tokens: exact full scan by the whole wave (deterministic)
  for (int t = 0; t < 8; t++) {
    int tb2 = w * 8 + t;
    if (cnt[tb2] > CAP) {
      const float* zq = zb + tb2;
      float Szn = __fadd_rn(Szp[0][tb2], Szp[1][tb2]);
      float bD = 3.4e38f;
      int bk = 0x7fffffff;
      for (int k = lane; k < K_CODES; k += 64) {
        const float* er = e + (size_t)k * DIM;
        float acc = 0.f;
#pragma unroll 4
        for (int dd = 0; dd < DIM; dd += 4) {
          float4 e4 = *(const float4*)(er + dd);
          acc = fmaf(zq[(size_t)(dd + 0) * SPATIAL], e4.x, acc);
          acc = fmaf(zq[(size_t)(dd + 1) * SPATIAL], e4.y, acc);
          acc = fmaf(zq[(size_t)(dd + 2) * SPATIAL], e4.z, acc);
          acc = fmaf(zq[(size_t)(dd + 3) * SPATIAL], e4.w, acc);
        }
        float D = __fsub_rn(__fadd_rn(Szn, Se[k]), __fmul_rn(2.f, acc));
        if (D < bD || (D == bD && k < bk)) { bD = D; bk = k; }
      }
#pragma unroll
      for (int m = 1; m < 64; m <<= 1) {
        float oD = __shfl_xor(bD, m);
        int ok = __shfl_xor(bk, m);
        if (oD < bD || (oD == bD && ok < bk)) { bD = oD; bk = ok; }
      }
      if (lane == 0) {
        mini_sh[tb2] = bk;
        out[O_IDX + n0 + tb2] = (float)bk;
      }
    }
  }
  __syncthreads();

  // ---- Phase E: quant gather + store + loss. lane = token (0..63);
  //      wave w covers dims [w*32, w*32+32); e-row read as float4 ----
  int mten = mini_sh[lane];
  const float* erow = e + (size_t)mten * DIM;
  float* op = out + (size_t)b * DIM * SPATIAL + s0;
  float sumsq = 0.f;
#pragma unroll 2
  for (int i4 = 0; i4 < 32; i4 += 4) {
    int d = w * 32 + i4;  // wave-uniform d, 16B-aligned
    float4 v4 = *(const float4*)(erow + d);
#pragma unroll
    for (int m = 0; m < 4; m++) {
      float v = (m == 0) ? v4.x : (m == 1) ? v4.y : (m == 2) ? v4.z : v4.w;
      float zv = zb[(size_t)(d + m) * SPATIAL + lane];
      float df = __fsub_rn(v, zv);
      sumsq = fmaf(df, df, sumsq);
      op[(size_t)(d + m) * SPATIAL + lane] = v;  // coalesced 64-wide store
    }
  }
#pragma unroll
  for (int o = 32; o > 0; o >>= 1) sumsq += __shfl_down(sumsq, o, 64);
  if (lane == 0) red[w] = sumsq;
  __syncthreads();
  if (tid == 0) {
    float rs = ((red[0] + red[1]) + (red[2] + red[3])) +
               ((red[4] + red[5]) + (red[6] + red[7]));
    atomicAdd(ws + WS_LOSS, rs);
    __threadfence();  // loss add globally visible before counter bump
    unsigned t = atomicAdd((unsigned*)ws + WS_CNT, 1u);
    if (t == NBLK - 1) {  // last block publishes loss
      float total = atomicAdd(ws + WS_LOSS, 0.f);  // device-scope read
      out[O_LOSS] = 1.25f * total / 8388608.f;
    }
  }
}

extern "C" void kernel_launch(void* const* d_in, const int* in_sizes, int n_in,
                              void* d_out, int out_size, void* d_ws, size_t ws_size,
                              hipStream_t stream) {
  const float* z = (const float*)d_in[0];
  const float* e = (const float*)d_in[1];
  float* ws = (float*)d_ws;
  float* out = (float*)d_out;

  prep_kernel<<<K_CODES, 256, 0, stream>>>(e, ws);
  main_kernel<<<NBLK, 512, 0, stream>>>(z, e, ws, out);
}